// Round 3
// baseline (454.797 us; speedup 1.0000x reference)
//
#include <hip/hip_runtime.h>

// Segmented max pooling, fixed-capacity bucket formulation.
//   K1 zero:        cnt[vt_out] = 0, ovf_n = 0                (1 MB)
//   K2 count+place: 4 rows/thread (nt int4 vt_map load);
//                   slot = atomicAdd(&cnt[seg],1);
//                   slot < 16 -> nt-store idx[seg*16+slot] = r
//                   else      -> overflow list (expected ~0 rows at lambda=4,
//                                but fully correct for any distribution)
//   K3 gather:      16-lane subgroup per segment (4 segments/wave);
//                   float4 row loads (16 x 16B = one 256B coalesced row),
//                   4-wide predicated batches for memory-level parallelism,
//                   no cross-lane reduction, 1 KiB contiguous store per wave.
// R6: nt hints on K3 input rows / K3 output / K2 vt_map (470 -> 449.5 us).
// R7 (this round): kill K2's idx write-allocate. The 4B scatters into the
// 16 MB idx region cause a 64B read-allocate per miss, repeated per-XCD
// (~64 MB of avoidable fetch). nt stores write through with byte masks --
// no fetch. Also: K2 coarsened to 4 rows/thread (1/4 the waves, 4
// independent atomics in flight), nt loads for K3 cnt/idx (read-once).
// NOTE: dur_us carries a ~290 us harness floor (1 GiB d_ws 0xAA poison fill
// at ~160 us + d_out poison + input restore are inside the timed region).

#define CCH 64
#define CAP 16
#define NEG_INF (-__builtin_huge_valf())

typedef float nt_f4 __attribute__((ext_vector_type(4)));
typedef int   nt_i4 __attribute__((ext_vector_type(4)));

__device__ __forceinline__ float4 nt_load_f4(const float4* p) {
    nt_f4 t = __builtin_nontemporal_load((const nt_f4*)p);
    return make_float4(t.x, t.y, t.z, t.w);
}
__device__ __forceinline__ void nt_store_f4(float4 v, float4* p) {
    nt_f4 t; t.x = v.x; t.y = v.y; t.z = v.z; t.w = v.w;
    __builtin_nontemporal_store(t, (nt_f4*)p);
}

__global__ void zero_kernel(int* __restrict__ p, int n) {
    int i = blockIdx.x * blockDim.x + threadIdx.x;
    if (i < n) p[i] = 0;
}

__global__ __launch_bounds__(256) void count_place_kernel(
                                   const int* __restrict__ vt_map,
                                   int* __restrict__ cnt,
                                   int* __restrict__ idx,
                                   int* __restrict__ ovf_n,
                                   int* __restrict__ ovf_rows,
                                   int n_in, int vt_out) {
    int t  = blockIdx.x * blockDim.x + threadIdx.x;
    int r0 = t * 4;
    if (r0 >= n_in) return;

    int s[4];
    if (r0 + 3 < n_in) {
        nt_i4 v = __builtin_nontemporal_load((const nt_i4*)(vt_map + r0));
        s[0] = v.x; s[1] = v.y; s[2] = v.z; s[3] = v.w;
    } else {
        for (int k = 0; k < 4; ++k)
            s[k] = (r0 + k < n_in) ? vt_map[r0 + k] : -1;
    }

#pragma unroll
    for (int k = 0; k < 4; ++k) {
        int seg = s[k];
        if (seg < 0 || seg >= vt_out) continue;
        int slot = atomicAdd(&cnt[seg], 1);
        if (slot < CAP) {
            // nt: 4B scattered store, write-through, no 64B read-allocate
            __builtin_nontemporal_store(r0 + k, &idx[seg * CAP + slot]);
        } else {
            int e = atomicAdd(ovf_n, 1);
            __builtin_nontemporal_store(r0 + k, &ovf_rows[e]);
        }
    }
}

__global__ __launch_bounds__(256) void bucket_gather_kernel(
        const float4* __restrict__ in4,
        const int* __restrict__ cnt,
        const int* __restrict__ idx,
        const int* __restrict__ ovf_n,
        const int* __restrict__ ovf_rows,
        const int* __restrict__ vt_map,
        float4* __restrict__ out4, int vt_out) {
    int wid  = blockIdx.x * 4 + (threadIdx.x >> 6);
    int lane = threadIdx.x & 63;
    int sub  = lane >> 4;          // subgroup 0..3, one segment each
    int g    = lane & 15;          // float4 column group within the row
    int seg  = wid * 4 + sub;
    if (seg >= vt_out) return;

    int c  = __builtin_nontemporal_load(&cnt[seg]);
    int rv = __builtin_nontemporal_load(&idx[seg * CAP + g]); // 16 lanes = 64B coalesced
    int cc = (c < CAP) ? c : CAP;

    float4 m = make_float4(NEG_INF, NEG_INF, NEG_INF, NEG_INF);
    for (int j = 0; j < cc; j += 4) {
        float4 v[4];
#pragma unroll
        for (int k = 0; k < 4; ++k) {
            int t  = j + k;
            int tt = (t < cc) ? t : (cc - 1);
            int rid = __shfl(rv, (sub << 4) + tt, 64);
            // streaming-once 256B row read: nt keeps L2 clean
            v[k] = nt_load_f4(&in4[(size_t)rid * 16 + g]);
        }
#pragma unroll
        for (int k = 0; k < 4; ++k) {
            if (j + k < cc) {
                m.x = fmaxf(m.x, v[k].x);
                m.y = fmaxf(m.y, v[k].y);
                m.z = fmaxf(m.z, v[k].z);
                m.w = fmaxf(m.w, v[k].w);
            }
        }
    }

    if (c > CAP) {                 // vanishingly rare; wave-uniform scan
        int ne = *ovf_n;
        for (int e = 0; e < ne; ++e) {
            int r = ovf_rows[e];
            if (vt_map[r] == seg) {
                float4 v = in4[(size_t)r * 16 + g];
                m.x = fmaxf(m.x, v.x);
                m.y = fmaxf(m.y, v.y);
                m.z = fmaxf(m.z, v.z);
                m.w = fmaxf(m.w, v.w);
            }
        }
    }

    float4 o;
    o.x = (m.x == NEG_INF) ? 0.0f : m.x;
    o.y = (m.y == NEG_INF) ? 0.0f : m.y;
    o.z = (m.z == NEG_INF) ? 0.0f : m.z;
    o.w = (m.w == NEG_INF) ? 0.0f : m.w;
    // streaming-once 1KB/wave contiguous store: bypass L2
    nt_store_f4(o, &out4[(size_t)seg * 16 + g]);
}

// ---------------- fallback: atomic scatter (R1) ----------------

__device__ __forceinline__ unsigned enc_f32(float f) {
    unsigned u = __float_as_uint(f);
    return (u & 0x80000000u) ? ~u : (u | 0x80000000u);
}
__device__ __forceinline__ float dec_f32(unsigned u) {
    unsigned b = (u & 0x80000000u) ? (u & 0x7fffffffu) : ~u;
    return __uint_as_float(b);
}
static constexpr unsigned ENC_NEG_INF = 0x007FFFFFu;

__global__ void pool_init_kernel(uint4* __restrict__ out, int n4) {
    int i = blockIdx.x * blockDim.x + threadIdx.x;
    if (i < n4) out[i] = make_uint4(ENC_NEG_INF, ENC_NEG_INF, ENC_NEG_INF, ENC_NEG_INF);
}
__global__ void pool_scatter_kernel(const float4* __restrict__ in,
                                    const int* __restrict__ vt_map,
                                    unsigned* __restrict__ out, int n_in, int vt_out) {
    int t = blockIdx.x * blockDim.x + threadIdx.x;
    int row = t >> 4, g = t & 15;
    if (row >= n_in) return;
    int seg = vt_map[row];
    if (seg < 0 || seg >= vt_out) return;
    float4 v = in[row * 16 + g];
    unsigned* dst = out + (size_t)seg * CCH + g * 4;
    atomicMax(dst + 0, enc_f32(v.x));
    atomicMax(dst + 1, enc_f32(v.y));
    atomicMax(dst + 2, enc_f32(v.z));
    atomicMax(dst + 3, enc_f32(v.w));
}
__global__ void pool_decode_kernel(uint4* __restrict__ out, int n4) {
    int i = blockIdx.x * blockDim.x + threadIdx.x;
    if (i >= n4) return;
    uint4 u = out[i];
    float4 f;
    f.x = (u.x == ENC_NEG_INF) ? 0.0f : dec_f32(u.x);
    f.y = (u.y == ENC_NEG_INF) ? 0.0f : dec_f32(u.y);
    f.z = (u.z == ENC_NEG_INF) ? 0.0f : dec_f32(u.z);
    f.w = (u.w == ENC_NEG_INF) ? 0.0f : dec_f32(u.w);
    ((float4*)out)[i] = f;
}

// ---------------- launch ----------------

extern "C" void kernel_launch(void* const* d_in, const int* in_sizes, int n_in_arr,
                              void* d_out, int out_size, void* d_ws, size_t ws_size,
                              hipStream_t stream) {
    const float* in     = (const float*)d_in[0];
    const int*   vt_map = (const int*)d_in[2];   // vt_replace (d_in[1]) unused for max
    float*       out    = (float*)d_out;

    const int n_in   = in_sizes[0] / CCH;   // 1048576
    const int vt_out = out_size / CCH;      // 262144
    const int B = 256;

    // ws layout: cnt[vt_out] | ovf_n[1] | idx[vt_out*CAP] | ovf_rows[n_in]
    const size_t ws_needed =
        ((size_t)vt_out * (CAP + 1) + 1 + (size_t)n_in) * sizeof(int);

    if (ws_size >= ws_needed) {
        int* cnt      = (int*)d_ws;
        int* ovf_n    = cnt + vt_out;
        int* idx      = ovf_n + 1;
        int* ovf_rows = idx + (size_t)vt_out * CAP;

        zero_kernel<<<(vt_out + 1 + B - 1) / B, B, 0, stream>>>(cnt, vt_out + 1);
        const int nt2 = (n_in + 3) / 4;               // 4 rows per thread
        count_place_kernel<<<(nt2 + B - 1) / B, B, 0, stream>>>(
            vt_map, cnt, idx, ovf_n, ovf_rows, n_in, vt_out);
        const int nwave = (vt_out + 3) / 4;           // 4 segments per wave
        bucket_gather_kernel<<<(nwave + 3) / 4, B, 0, stream>>>(
            (const float4*)in, cnt, idx, ovf_n, ovf_rows, vt_map,
            (float4*)out, vt_out);
    } else {
        unsigned* out_u = (unsigned*)d_out;
        const int n4 = out_size / 4;
        pool_init_kernel<<<(n4 + B - 1) / B, B, 0, stream>>>((uint4*)out_u, n4);
        pool_scatter_kernel<<<(n_in * 16 + B - 1) / B, B, 0, stream>>>(
            (const float4*)in, vt_map, out_u, n_in, vt_out);
        pool_decode_kernel<<<(n4 + B - 1) / B, B, 0, stream>>>((uint4*)out_u, n4);
    }
}

// Round 4
// 441.937 us; speedup vs baseline: 1.0291x; 1.0291x over previous
//
#include <hip/hip_runtime.h>

// Segmented max pooling, fixed-capacity bucket formulation.
//   K1 zero:        cnt[vt_out] = 0, ovf_n = 0                (1 MB)
//   K2 count+place: slot = atomicAdd(&cnt[seg],1);
//                   slot < 16 -> idx[seg*16+slot] = r   (plain store: L2
//                   absorbs ~4 stores/line via byte-masked dirty lines;
//                   R7 proved nt write-through here REGRESSES +5us)
//                   else      -> overflow list (expected ~0 rows at lambda=4,
//                                but fully correct for any distribution)
//   K3 gather:      16-lane subgroup per segment (4 segments/wave);
//                   float4 row loads (16 x 16B = one 256B coalesced row),
//                   4-wide PREDICATED batches (R8: no clamped duplicate
//                   loads for cc<4 segments), no cross-lane reduction,
//                   1 KiB contiguous store per wave.
// R6: nt hints on K3 input rows / K3 output / K2 vt_map (470 -> 449.5 us).
// R7: nt idx stores + K2 coarsening -> 454.8 us REGRESSION; reverted.
// R8 (this round): R6 exact + predicated K3 batch loads.
// NOTE: dur_us carries a ~290 us harness floor (1 GiB d_ws 0xAA poison fill
// at ~160 us + d_out poison + input restore are inside the timed region).

#define CCH 64
#define CAP 16
#define NEG_INF (-__builtin_huge_valf())

typedef float nt_f4 __attribute__((ext_vector_type(4)));

__device__ __forceinline__ float4 nt_load_f4(const float4* p) {
    nt_f4 t = __builtin_nontemporal_load((const nt_f4*)p);
    return make_float4(t.x, t.y, t.z, t.w);
}
__device__ __forceinline__ void nt_store_f4(float4 v, float4* p) {
    nt_f4 t; t.x = v.x; t.y = v.y; t.z = v.z; t.w = v.w;
    __builtin_nontemporal_store(t, (nt_f4*)p);
}

__global__ void zero_kernel(int* __restrict__ p, int n) {
    int i = blockIdx.x * blockDim.x + threadIdx.x;
    if (i < n) p[i] = 0;
}

__global__ __launch_bounds__(256) void count_place_kernel(
                                   const int* __restrict__ vt_map,
                                   int* __restrict__ cnt,
                                   int* __restrict__ idx,
                                   int* __restrict__ ovf_n,
                                   int* __restrict__ ovf_rows,
                                   int n_in, int vt_out) {
    int r = blockIdx.x * blockDim.x + threadIdx.x;
    if (r >= n_in) return;
    int seg = __builtin_nontemporal_load(&vt_map[r]);
    if (seg < 0 || seg >= vt_out) return;
    int slot = atomicAdd(&cnt[seg], 1);
    if (slot < CAP) {
        idx[seg * CAP + slot] = r;
    } else {
        int e = atomicAdd(ovf_n, 1);
        ovf_rows[e] = r;           // capacity n_in reserved: cannot overflow
    }
}

__global__ __launch_bounds__(256) void bucket_gather_kernel(
        const float4* __restrict__ in4,
        const int* __restrict__ cnt,
        const int* __restrict__ idx,
        const int* __restrict__ ovf_n,
        const int* __restrict__ ovf_rows,
        const int* __restrict__ vt_map,
        float4* __restrict__ out4, int vt_out) {
    int wid  = blockIdx.x * 4 + (threadIdx.x >> 6);
    int lane = threadIdx.x & 63;
    int sub  = lane >> 4;          // subgroup 0..3, one segment each
    int g    = lane & 15;          // float4 column group within the row
    int seg  = wid * 4 + sub;
    if (seg >= vt_out) return;

    int c  = cnt[seg];
    int rv = idx[seg * CAP + g];   // 16 lanes hold the segment's 16 slots (64B coalesced)
    int cc = (c < CAP) ? c : CAP;

    float4 m = make_float4(NEG_INF, NEG_INF, NEG_INF, NEG_INF);
    for (int j = 0; j < cc; j += 4) {
        float4 v[4];
#pragma unroll
        for (int k = 0; k < 4; ++k) {
            // shfl is safe for any slot value; only dereference when valid.
            int rid = __shfl(rv, (sub << 4) + (j + k), 64);
            v[k] = make_float4(NEG_INF, NEG_INF, NEG_INF, NEG_INF);
            if (j + k < cc)
                v[k] = nt_load_f4(&in4[(size_t)rid * 16 + g]);  // 256B row
        }
#pragma unroll
        for (int k = 0; k < 4; ++k) {
            m.x = fmaxf(m.x, v[k].x);
            m.y = fmaxf(m.y, v[k].y);
            m.z = fmaxf(m.z, v[k].z);
            m.w = fmaxf(m.w, v[k].w);
        }
    }

    if (c > CAP) {                 // vanishingly rare; wave-uniform scan
        int ne = *ovf_n;
        for (int e = 0; e < ne; ++e) {
            int r = ovf_rows[e];
            if (vt_map[r] == seg) {
                float4 v = in4[(size_t)r * 16 + g];
                m.x = fmaxf(m.x, v.x);
                m.y = fmaxf(m.y, v.y);
                m.z = fmaxf(m.z, v.z);
                m.w = fmaxf(m.w, v.w);
            }
        }
    }

    float4 o;
    o.x = (m.x == NEG_INF) ? 0.0f : m.x;
    o.y = (m.y == NEG_INF) ? 0.0f : m.y;
    o.z = (m.z == NEG_INF) ? 0.0f : m.z;
    o.w = (m.w == NEG_INF) ? 0.0f : m.w;
    // streaming-once 1KB/wave contiguous store: bypass L2
    nt_store_f4(o, &out4[(size_t)seg * 16 + g]);
}

// ---------------- fallback: atomic scatter (R1) ----------------

__device__ __forceinline__ unsigned enc_f32(float f) {
    unsigned u = __float_as_uint(f);
    return (u & 0x80000000u) ? ~u : (u | 0x80000000u);
}
__device__ __forceinline__ float dec_f32(unsigned u) {
    unsigned b = (u & 0x80000000u) ? (u & 0x7fffffffu) : ~u;
    return __uint_as_float(b);
}
static constexpr unsigned ENC_NEG_INF = 0x007FFFFFu;

__global__ void pool_init_kernel(uint4* __restrict__ out, int n4) {
    int i = blockIdx.x * blockDim.x + threadIdx.x;
    if (i < n4) out[i] = make_uint4(ENC_NEG_INF, ENC_NEG_INF, ENC_NEG_INF, ENC_NEG_INF);
}
__global__ void pool_scatter_kernel(const float4* __restrict__ in,
                                    const int* __restrict__ vt_map,
                                    unsigned* __restrict__ out, int n_in, int vt_out) {
    int t = blockIdx.x * blockDim.x + threadIdx.x;
    int row = t >> 4, g = t & 15;
    if (row >= n_in) return;
    int seg = vt_map[row];
    if (seg < 0 || seg >= vt_out) return;
    float4 v = in[row * 16 + g];
    unsigned* dst = out + (size_t)seg * CCH + g * 4;
    atomicMax(dst + 0, enc_f32(v.x));
    atomicMax(dst + 1, enc_f32(v.y));
    atomicMax(dst + 2, enc_f32(v.z));
    atomicMax(dst + 3, enc_f32(v.w));
}
__global__ void pool_decode_kernel(uint4* __restrict__ out, int n4) {
    int i = blockIdx.x * blockDim.x + threadIdx.x;
    if (i >= n4) return;
    uint4 u = out[i];
    float4 f;
    f.x = (u.x == ENC_NEG_INF) ? 0.0f : dec_f32(u.x);
    f.y = (u.y == ENC_NEG_INF) ? 0.0f : dec_f32(u.y);
    f.z = (u.z == ENC_NEG_INF) ? 0.0f : dec_f32(u.z);
    f.w = (u.w == ENC_NEG_INF) ? 0.0f : dec_f32(u.w);
    ((float4*)out)[i] = f;
}

// ---------------- launch ----------------

extern "C" void kernel_launch(void* const* d_in, const int* in_sizes, int n_in_arr,
                              void* d_out, int out_size, void* d_ws, size_t ws_size,
                              hipStream_t stream) {
    const float* in     = (const float*)d_in[0];
    const int*   vt_map = (const int*)d_in[2];   // vt_replace (d_in[1]) unused for max
    float*       out    = (float*)d_out;

    const int n_in   = in_sizes[0] / CCH;   // 1048576
    const int vt_out = out_size / CCH;      // 262144
    const int B = 256;

    // ws layout: cnt[vt_out] | ovf_n[1] | idx[vt_out*CAP] | ovf_rows[n_in]
    const size_t ws_needed =
        ((size_t)vt_out * (CAP + 1) + 1 + (size_t)n_in) * sizeof(int);

    if (ws_size >= ws_needed) {
        int* cnt      = (int*)d_ws;
        int* ovf_n    = cnt + vt_out;
        int* idx      = ovf_n + 1;
        int* ovf_rows = idx + (size_t)vt_out * CAP;

        zero_kernel<<<(vt_out + 1 + B - 1) / B, B, 0, stream>>>(cnt, vt_out + 1);
        count_place_kernel<<<(n_in + B - 1) / B, B, 0, stream>>>(
            vt_map, cnt, idx, ovf_n, ovf_rows, n_in, vt_out);
        const int nwave = (vt_out + 3) / 4;           // 4 segments per wave
        bucket_gather_kernel<<<(nwave + 3) / 4, B, 0, stream>>>(
            (const float4*)in, cnt, idx, ovf_n, ovf_rows, vt_map,
            (float4*)out, vt_out);
    } else {
        unsigned* out_u = (unsigned*)d_out;
        const int n4 = out_size / 4;
        pool_init_kernel<<<(n4 + B - 1) / B, B, 0, stream>>>((uint4*)out_u, n4);
        pool_scatter_kernel<<<(n_in * 16 + B - 1) / B, B, 0, stream>>>(
            (const float4*)in, vt_map, out_u, n_in, vt_out);
        pool_decode_kernel<<<(n4 + B - 1) / B, B, 0, stream>>>((uint4*)out_u, n4);
    }
}